// Round 8
// baseline (310.061 us; speedup 1.0000x reference)
//
#include <hip/hip_runtime.h>
#include <cstddef>

#define H 128
#define W 192
#define KS 31
#define CF 64
#define NPIX (H*W)          // 24576
#define NKL (KS*KS)         // 961

// d_out layout (floats): out | pos | enorm | weights
#define OFF_POS (3*NPIX)            // 73728
#define OFF_EN  (OFF_POS + 2*NPIX)  // 122880
#define OFF_WGT (OFF_EN + NPIX)     // 147456

// workspace layout (floats)
#define NIMG NPIX
#define WS_CWT 0
#define WS_SWT 512
#define WS_CHT 1024
#define WS_SHT 1536
#define WS_U   2048                          // UV interleaved: 2*128*NIMG floats
#define WS_Y   (WS_U + 2*128*NIMG)
#define WS_SN  (WS_Y + 128*NIMG)            // ushort[NPIX*64] viewed as floats
#define WS_TN  (WS_SN + 32*NIMG)

#define PI_F 3.14159265358979323846f
#define ELS 962                              // eL row stride (ushorts); 962%64==2

typedef __attribute__((ext_vector_type(8))) short short8v;
typedef __attribute__((ext_vector_type(4))) float f32x4;

__device__ inline ushort bf16rtn(float f){
  uint u = __float_as_uint(f);
  u += 0x7fffu + ((u >> 16) & 1u);
  return (ushort)(u >> 16);
}
__device__ inline float bf2f(ushort h){ return __uint_as_float((uint)h << 16); }

// ---------------- K1: filter tables (exact DFT sums, integer mod reduction) ---
__global__ __launch_bounds__(256) void k_tables(float* ws){
  int t = blockIdx.x*256 + threadIdx.x;
  if (t < 383){
    int d = t - 191;
    float c = 1.0f, s = 0.0f;
    for (int v = 1; v < 48; ++v){
      int m = (v*d) % 192; if (m < 0) m += 192;
      float a = (2.0f*PI_F/192.0f)*(float)m;
      c += 2.0f*cosf(a);
      s += 2.0f*sinf(a);
    }
    ws[WS_CWT + t] = c * (1.0f/192.0f);
    ws[WS_SWT + t] = s * (1.0f/192.0f);
  } else if (t < 383 + 255){
    int i = t - 383;
    int d = i - 127;
    float c = 0.0f, s = 0.0f;
    for (int u = 0; u < 32; ++u){
      int m = (u*d) % 128; if (m < 0) m += 128;
      float a = (2.0f*PI_F/128.0f)*(float)m;
      c += cosf(a);
      s += sinf(a);
    }
    ws[WS_CHT + i] = c * (1.0f/128.0f);
    ws[WS_SHT + i] = s * (1.0f/128.0f);
  }
}

// ---------------- K2: column pass  UV = x * {cwt,swt}, float2 out -------------
__global__ __launch_bounds__(192) void k_colpass(const float* __restrict__ feats,
                                                const float* __restrict__ ws,
                                                float2* __restrict__ UV2){
  __shared__ float xs[16][192];
  __shared__ float tc[4][392], tn[4][392];
  int w  = threadIdx.x;
  int R0 = blockIdx.x * 16;
  for (int i = w; i < 380; i += 192){
#pragma unroll
    for (int s = 0; s < 4; ++s){
      tc[s][i] = ws[WS_CWT + i + s];     // i+s <= 382, table len 383
      tn[s][i] = ws[WS_SWT + i + s];
    }
  }
#pragma unroll
  for (int r = 0; r < 16; ++r) xs[r][w] = feats[(size_t)(R0 + r)*192 + w];
  __syncthreads();

  const int s = w & 3;
  const int boff = (w & ~3) + 188;           // (w - s) + 188, %4 == 0
  const float* tcs = tc[s];
  const float* tns = tn[s];

  float u[16], v[16];
#pragma unroll
  for (int r = 0; r < 16; ++r){ u[r] = 0.0f; v[r] = 0.0f; }

  for (int wp0 = 0; wp0 < 192; wp0 += 4){
    const float4 cw4 = *reinterpret_cast<const float4*>(tcs + (boff - wp0));
    const float4 sw4 = *reinterpret_cast<const float4*>(tns + (boff - wp0));
    // c(wp0+j) = cw4[3-j]
#pragma unroll
    for (int r = 0; r < 16; ++r){
      const float4 x4 = *reinterpret_cast<const float4*>(&xs[r][wp0]);
      u[r] = fmaf(x4.x, cw4.w, u[r]);
      u[r] = fmaf(x4.y, cw4.z, u[r]);
      u[r] = fmaf(x4.z, cw4.y, u[r]);
      u[r] = fmaf(x4.w, cw4.x, u[r]);
      v[r] = fmaf(x4.x, sw4.w, v[r]);
      v[r] = fmaf(x4.y, sw4.z, v[r]);
      v[r] = fmaf(x4.z, sw4.y, v[r]);
      v[r] = fmaf(x4.w, sw4.x, v[r]);
    }
  }
#pragma unroll
  for (int r = 0; r < 16; ++r)
    UV2[(size_t)(R0 + r)*192 + w] = make_float2(u[r], v[r]);
}

// ---------------- K3: row pass  y = Ch*U + (-Sh)*V ----------------------------
__global__ __launch_bounds__(192) void k_rowpass(const float2* __restrict__ UV2,
                                                const float* __restrict__ ws,
                                                float* __restrict__ Y){
  __shared__ float Lc[4][144], Ls[4][144];
  int w = threadIdx.x;
  int ch = blockIdx.x >> 3;
  int h0 = (blockIdx.x & 7) * 16;
  for (int i = w; i < 143; i += 192){
#pragma unroll
    for (int s = 0; s < 4; ++s){
      int gi = h0 + i + s;
      Lc[s][i] = (gi < 255) ?  ws[WS_CHT + gi] : 0.0f;
      Ls[s][i] = (gi < 255) ? -ws[WS_SHT + gi] : 0.0f;   // negated
    }
  }
  __syncthreads();
  const float2* Uc = UV2 + (size_t)ch*NIMG;

  float acc[16];
#pragma unroll
  for (int r = 0; r < 16; ++r) acc[r] = 0.0f;

  for (int hp0 = 0; hp0 < 128; hp0 += 4){
    float2 uv0 = Uc[(hp0+0)*192 + w];
    float2 uv1 = Uc[(hp0+1)*192 + w];
    float2 uv2 = Uc[(hp0+2)*192 + w];
    float2 uv3 = Uc[(hp0+3)*192 + w];
#pragma unroll
    for (int r = 0; r < 16; ++r){
      int lb = 124 + (r & ~3) - hp0;          // (124 + r - hp0) - (r&3), %4==0
      const float4 c4 = *reinterpret_cast<const float4*>(&Lc[r & 3][lb]);
      const float4 s4 = *reinterpret_cast<const float4*>(&Ls[r & 3][lb]);
      // cht(h0+r-hp0-j+127) = c4[3-j]
      acc[r] = fmaf(uv0.x, c4.w, acc[r]);
      acc[r] = fmaf(uv0.y, s4.w, acc[r]);
      acc[r] = fmaf(uv1.x, c4.z, acc[r]);
      acc[r] = fmaf(uv1.y, s4.z, acc[r]);
      acc[r] = fmaf(uv2.x, c4.y, acc[r]);
      acc[r] = fmaf(uv2.y, s4.y, acc[r]);
      acc[r] = fmaf(uv3.x, c4.x, acc[r]);
      acc[r] = fmaf(uv3.y, s4.x, acc[r]);
    }
  }
#pragma unroll
  for (int r = 0; r < 16; ++r)
    Y[(size_t)ch*NIMG + (h0 + r)*192 + w] = acc[r];
}

// ---------------- K4: per-pixel channel normalization -> bf16 (h,w,c) ---------
__global__ __launch_bounds__(192) void k_norm(const float* __restrict__ Y,
                                              ushort* __restrict__ SNh,
                                              ushort* __restrict__ TNh){
  int h = blockIdx.x, w = threadIdx.x;
  int which = blockIdx.y;                // 0 = src, 1 = tgt
  int pix = h*192 + w;
  const float* base = Y + (size_t)which*64*NIMG + pix;
  float x[64];
  float ss = 0.0f;
#pragma unroll
  for (int c = 0; c < 64; ++c){
    x[c] = base[(size_t)c*NIMG];
    ss = fmaf(x[c], x[c], ss);
  }
  float rn = 1.0f / sqrtf(ss);
  ushort* o = (which ? TNh : SNh) + (size_t)pix*64;
#pragma unroll
  for (int q = 0; q < 8; ++q){
    ushort tmp[8];
#pragma unroll
    for (int e = 0; e < 8; ++e) tmp[e] = bf16rtn(x[q*8 + e] * rn);
    *reinterpret_cast<uint4*>(o + q*8) = *reinterpret_cast<const uint4*>(tmp);
  }
}

// ---------------- K5: fused corr + softmax + outputs, bf16 LDS e-cache --------
// Block = (h, 16-w tile), 4 waves, ~39KB LDS -> 4 blocks/CU.  |logit| <= temp
// (unit vectors) => fixed offset exp(s-temp), no max pass.  Weights written
// with NONTEMPORAL stores: write-once stream must not RFO/thrash L2.
__global__ __launch_bounds__(256, 4) void k_corrsm(const ushort* __restrict__ SNh,
                                                   const ushort* __restrict__ TNh,
                                                   const int* __restrict__ temp,
                                                   const float* __restrict__ frames,
                                                   float* __restrict__ dout){
  __shared__ ushort eLu[16*ELS];         // bf16 e-cache, row stride 962
  __shared__ float red7[7][16][16];
  __shared__ float rsw[16];
  int h  = blockIdx.x;
  int bx = blockIdx.y;                   // w-tile 0..11
  int t  = threadIdx.x;
  int lane = t & 63, wv = t >> 6;
  int n = lane & 15, g = lane >> 4;
  int w0 = bx * 16;
  float tempf = (float)(*temp);

  const ushort* ap = TNh + ((size_t)(h*192 + w0 + n))*64 + g*8;
  short8v a0 = *reinterpret_cast<const short8v*>(ap);
  short8v a1 = *reinterpret_cast<const short8v*>(ap + 32);

  // ---- fill pass: waves split k ----
  for (int k = wv; k < KS; k += 4){
    int sh = h + k - 15; sh = sh < 0 ? 0 : (sh > 127 ? 127 : sh);
    const ushort* srow = SNh + (size_t)sh*192*64;
#pragma unroll
    for (int dj = 0; dj < 3; ++dj){
      int j0 = bx - 1 + dj;
      if (j0 < 0 || j0 > 11) continue;
      const ushort* bp = srow + ((size_t)(j0*16 + n))*64 + g*8;
      short8v b0 = *reinterpret_cast<const short8v*>(bp);
      short8v b1 = *reinterpret_cast<const short8v*>(bp + 32);
      f32x4 acc = {0.0f, 0.0f, 0.0f, 0.0f};
      acc = __builtin_amdgcn_mfma_f32_16x16x32_bf16(a0, b0, acc, 0, 0, 0);
      acc = __builtin_amdgcn_mfma_f32_16x16x32_bf16(a1, b1, acc, 0, 0, 0);
      int sx = j0*16 + n;
#pragma unroll
      for (int r = 0; r < 4; ++r){
        int wl = g*4 + r;
        int wg = w0 + wl;
        int l = sx - wg + 15;
        float e = __expf(acc[r]*tempf - tempf);
        ushort eb = bf16rtn(e);
        if (l >= 0 && l <= 30) eLu[wl*ELS + k*31 + l] = eb;
        if (bx == 0 && j0 == 0 && n == 0){          // left edge -> col 0
          for (int l2 = 0; l2 < 15 - wg; ++l2) eLu[wl*ELS + k*31 + l2] = eb;
        }
        if (bx == 11 && j0 == 11 && n == 15){       // right edge -> col 191
          for (int l2 = 207 - wg; l2 <= 30; ++l2) eLu[wl*ELS + k*31 + l2] = eb;
        }
      }
    }
  }
  __syncthreads();

  // ---- reduction pass: thread t -> w = t&15, k in {t>>4, t>>4+16} ----
  {
    float s=0, o0=0, o1=0, o2=0, p0=0, p1=0, en=0;
    int wl = t & 15;
    int wg = w0 + wl;
    for (int kk = t >> 4; kk < KS; kk += 16){
      int sh = h + kk - 15; sh = sh < 0 ? 0 : (sh > 127 ? 127 : sh);
      float dy = (float)(kk - 15);
      float dy2 = dy*dy;
      const float* f0p = frames + sh*192;
      const float* f1p = f0p + NPIX;
      const float* f2p = f0p + 2*NPIX;
      const ushort* src = eLu + wl*ELS + kk*31;
#pragma unroll
      for (int l = 0; l < KS; ++l){
        float e = bf2f(src[l]);
        float dx = (float)(l - 15);
        int ww = wg + l - 15; ww = ww < 0 ? 0 : (ww > 191 ? 191 : ww);
        s  += e;
        p0 = fmaf(e, dx, p0);
        p1 = fmaf(e, dy, p1);
        en = fmaf(e, sqrtf(dx*dx + dy2), en);
        o0 = fmaf(e, f0p[ww], o0);
        o1 = fmaf(e, f1p[ww], o1);
        o2 = fmaf(e, f2p[ww], o2);
      }
    }
    int q = t >> 4;
    red7[0][q][wl]=s;  red7[1][q][wl]=o0; red7[2][q][wl]=o1; red7[3][q][wl]=o2;
    red7[4][q][wl]=p0; red7[5][q][wl]=p1; red7[6][q][wl]=en;
  }
  __syncthreads();

  if (t < 16){
    float a[7];
#pragma unroll
    for (int j = 0; j < 7; ++j){
      float acc = 0.0f;
#pragma unroll
      for (int qq = 0; qq < 16; ++qq) acc += red7[j][qq][t];
      a[j] = acc;
    }
    float rs = 1.0f / a[0];
    int pix = h*192 + w0 + t;
    dout[0*NPIX + pix] = a[1]*rs;
    dout[1*NPIX + pix] = a[2]*rs;
    dout[2*NPIX + pix] = a[3]*rs;
    dout[OFF_POS + pix*2 + 0] = a[4]*rs;
    dout[OFF_POS + pix*2 + 1] = a[5]*rs;
    dout[OFF_EN + pix] = a[6]*rs;
    rsw[t] = rs;
  }
  __syncthreads();

  // ---- write pass: wave wv -> rows 4wv..4wv+3; 64 lanes = 256B contiguous ----
  // Nontemporal: write-once stream, bypass L2 write-allocate.
#pragma unroll
  for (int rr = 0; rr < 4; ++rr){
    int row = wv*4 + rr;
    float rsv = rsw[row];
    float* dst = dout + OFF_WGT + ((size_t)(h*192 + w0 + row))*NKL;
    const ushort* src = eLu + row*ELS;
#pragma unroll
    for (int i = 0; i < 15; ++i){
      int j = i*64 + lane;
      __builtin_nontemporal_store(bf2f(src[j]) * rsv, dst + j);
    }
    if (lane == 0) __builtin_nontemporal_store(bf2f(src[960]) * rsv, dst + 960);
  }
}

extern "C" void kernel_launch(void* const* d_in, const int* in_sizes, int n_in,
                              void* d_out, int out_size, void* d_ws, size_t ws_size,
                              hipStream_t stream) {
  const float* frames = (const float*)d_in[0];   // (1,1,3,128,192)
  const float* feats  = (const float*)d_in[2];   // (1,2,64,128,192)
  const int*   temp   = (const int*)d_in[3];
  float* ws   = (float*)d_ws;
  float* dout = (float*)d_out;
  (void)in_sizes; (void)n_in; (void)out_size; (void)ws_size;

  float2* UV2 = (float2*)(ws + WS_U);
  float*  Y   = ws + WS_Y;
  ushort* SNh = (ushort*)(ws + WS_SN);
  ushort* TNh = (ushort*)(ws + WS_TN);

  hipLaunchKernelGGL(k_tables,  dim3(3),        dim3(256), 0, stream, ws);
  hipLaunchKernelGGL(k_colpass, dim3(1024),     dim3(192), 0, stream, feats, ws, UV2);
  hipLaunchKernelGGL(k_rowpass, dim3(1024),     dim3(192), 0, stream, UV2, ws, Y);
  hipLaunchKernelGGL(k_norm,    dim3(128, 2),   dim3(192), 0, stream, Y, SNh, TNh);
  hipLaunchKernelGGL(k_corrsm,  dim3(128, 12),  dim3(256), 0, stream, SNh, TNh, temp, frames, dout);
}